// Round 3
// baseline (661.750 us; speedup 1.0000x reference)
//
#include <hip/hip_runtime.h>

#define EPS 1e-5f

// dims: feat (2,128,128,128), guide (2,3,256,256), out (2,128,256,256)
// E=32, K=3, k2=9. H2=W2=256.

// ---- conv1: guide 3->32, LDS-tiled -------------------------------------
__global__ __launch_bounds__(256) void k_conv1_t(
    const float* __restrict__ guide, const float* __restrict__ w1,
    float* __restrict__ x1)
{
    __shared__ float sm[3][342];           // 18 rows * stride 19
    int tid = threadIdx.x;
    int b = blockIdx.x >> 8;
    int tile = blockIdx.x & 255;
    int ty0 = (tile >> 4) << 4, tx0 = (tile & 15) << 4;

    for (int i = tid; i < 972; i += 256) { // 3 * 324
        int c = i / 324;
        int rem = i - c * 324;
        int r = rem / 18, cl = rem - r * 18;
        int yy = ty0 + r - 1, xx = tx0 + cl - 1;
        float v = 0.f;
        if (yy >= 0 && yy < 256 && xx >= 0 && xx < 256)
            v = guide[((b * 3 + c) * 256 + yy) * 256 + xx];
        sm[c][r * 19 + cl] = v;
    }
    __syncthreads();

    int r = tid >> 4, cl = tid & 15;
    float t[27];
#pragma unroll
    for (int c = 0; c < 3; ++c)
#pragma unroll
        for (int ky = 0; ky < 3; ++ky)
#pragma unroll
            for (int kx = 0; kx < 3; ++kx)
                t[c * 9 + ky * 3 + kx] = sm[c][(r + ky) * 19 + cl + kx];
    int y = ty0 + r, x = tx0 + cl;
#pragma unroll 4
    for (int e = 0; e < 32; ++e) {
        float acc = 0.f;
#pragma unroll
        for (int k = 0; k < 27; ++k)
            acc += t[k] * w1[e * 27 + k];
        x1[((b * 32 + e) * 256 + y) * 256 + x] = acc;
    }
}

// ---- batch stats -> a,b ------------------------------------------------
__global__ __launch_bounds__(256) void k_stats(
    const float* __restrict__ xin, const float* __restrict__ gamma,
    const float* __restrict__ beta, float* __restrict__ ab)
{
    int c = blockIdx.x, tid = threadIdx.x;
    float s = 0.f, ss = 0.f;
    for (int b = 0; b < 2; ++b) {
        const float* p = xin + (size_t)(b * 32 + c) * 65536;
        for (int i = tid; i < 65536; i += 256) {
            float v = p[i];
            s += v; ss += v * v;
        }
    }
    __shared__ float rs[256], rss[256];
    rs[tid] = s; rss[tid] = ss;
    __syncthreads();
    for (int o = 128; o > 0; o >>= 1) {
        if (tid < o) { rs[tid] += rs[tid + o]; rss[tid] += rss[tid + o]; }
        __syncthreads();
    }
    if (tid == 0) {
        const float n = 131072.f;
        float mean = rs[0] / n;
        float var = rss[0] / n - mean * mean;
        float a = gamma[c] * rsqrtf(var + EPS);
        ab[c] = a;
        ab[32 + c] = beta[c] - mean * a;
    }
}

// ---- conv2: bnrelu(x1) 32->32, LDS-tiled -------------------------------
__global__ __launch_bounds__(256) void k_conv2_t(
    const float* __restrict__ x1, const float* __restrict__ ab1,
    const float* __restrict__ w2, float* __restrict__ x2)
{
    __shared__ float sm[32][342];          // 43.8 KB
    int tid = threadIdx.x;
    int b = blockIdx.x >> 8;
    int tile = blockIdx.x & 255;
    int ty0 = (tile >> 4) << 4, tx0 = (tile & 15) << 4;

    for (int i = tid; i < 10368; i += 256) {  // 32 * 324
        int c = i / 324;
        int rem = i - c * 324;
        int r = rem / 18, cl = rem - r * 18;
        int yy = ty0 + r - 1, xx = tx0 + cl - 1;
        float v = 0.f;
        if (yy >= 0 && yy < 256 && xx >= 0 && xx < 256)
            v = fmaxf(ab1[c] * x1[((b * 32 + c) * 256 + yy) * 256 + xx] + ab1[32 + c], 0.f);
        sm[c][r * 19 + cl] = v;
    }
    __syncthreads();

    int r = tid >> 4, cl = tid & 15;
    float acc[32];
#pragma unroll
    for (int e = 0; e < 32; ++e) acc[e] = 0.f;
#pragma unroll 1
    for (int c = 0; c < 32; ++c) {
        float t[9];
#pragma unroll
        for (int ky = 0; ky < 3; ++ky)
#pragma unroll
            for (int kx = 0; kx < 3; ++kx)
                t[ky * 3 + kx] = sm[c][(r + ky) * 19 + cl + kx];
#pragma unroll
        for (int e = 0; e < 32; ++e)
#pragma unroll
            for (int k = 0; k < 9; ++k)
                acc[e] += t[k] * w2[(e * 32 + c) * 9 + k];
    }
    int y = ty0 + r, x = tx0 + cl;
#pragma unroll
    for (int e = 0; e < 32; ++e)
        x2[((b * 32 + e) * 256 + y) * 256 + x] = acc[e];
}

// ---- 1x1 proj at lowres, 4 threads/pixel -------------------------------
__global__ __launch_bounds__(256) void k_proj2(
    const float* __restrict__ feat, const float* __restrict__ pw,
    float* __restrict__ fs)
{
    int tid = threadIdx.x;
    unsigned pix = blockIdx.x * 64u + (tid & 63);   // 0..32767
    int q = tid >> 6;                               // e-quarter
    int x = pix & 127, y = (pix >> 7) & 127, b = pix >> 14;
    float acc[8];
#pragma unroll
    for (int e = 0; e < 8; ++e) acc[e] = 0.f;
#pragma unroll 4
    for (int c = 0; c < 128; ++c) {
        float v = feat[((b * 128 + c) * 128 + y) * 128 + x];
#pragma unroll
        for (int e = 0; e < 8; ++e)
            acc[e] += v * pw[(q * 8 + e) * 128 + c];
    }
#pragma unroll
    for (int e = 0; e < 8; ++e) {
        float v = acc[e];
        fs[((b * 32 + q * 8 + e) * 128 + y) * 128 + x] = v > 0.f ? v : 0.f;
    }
}

// ---- kernel head: conv3x3 64->32 + ReLU + 1x1->9 + softmax, LDS-tiled --
__global__ __launch_bounds__(256) void k_kern_t(
    const float* __restrict__ x2, const float* __restrict__ ab2,
    const float* __restrict__ fs, const float* __restrict__ kw1,
    const float* __restrict__ kw2, const float* __restrict__ kb2,
    float* __restrict__ kern)
{
    __shared__ float smg[32][342];   // 43.8 KB: bnrelu(x2) halo tile
    __shared__ float smf[32][110];   // 14.1 KB: fs lowres 10x10 tile
    int tid = threadIdx.x;
    int b = blockIdx.x >> 8;
    int tile = blockIdx.x & 255;
    int ty0 = (tile >> 4) << 4, tx0 = (tile & 15) << 4;

    for (int i = tid; i < 10368; i += 256) {
        int c = i / 324;
        int rem = i - c * 324;
        int r = rem / 18, cl = rem - r * 18;
        int yy = ty0 + r - 1, xx = tx0 + cl - 1;
        float v = 0.f;
        if (yy >= 0 && yy < 256 && xx >= 0 && xx < 256)
            v = fmaxf(ab2[c] * x2[((b * 32 + c) * 256 + yy) * 256 + xx] + ab2[32 + c], 0.f);
        smg[c][r * 19 + cl] = v;
    }
    int ly0 = (ty0 >> 1) - 1, lx0 = (tx0 >> 1) - 1;
    for (int i = tid; i < 3200; i += 256) {   // 32 * 100
        int c = i / 100;
        int rem = i - c * 100;
        int r = rem / 10, cl = rem - r * 10;
        int yy = ly0 + r, xx = lx0 + cl;
        float v = 0.f;
        if (yy >= 0 && yy < 128 && xx >= 0 && xx < 128)
            v = fs[((b * 32 + c) * 128 + yy) * 128 + xx];
        smf[c][r * 11 + cl] = v;
    }
    __syncthreads();

    int r = tid >> 4, cl = tid & 15;
    int y = ty0 + r, x = tx0 + cl;
    float acc[32];
#pragma unroll
    for (int e = 0; e < 32; ++e) acc[e] = 0.f;

    // g half (channels 0..31)
#pragma unroll 1
    for (int c = 0; c < 32; ++c) {
        float t[9];
#pragma unroll
        for (int ky = 0; ky < 3; ++ky)
#pragma unroll
            for (int kx = 0; kx < 3; ++kx)
                t[ky * 3 + kx] = smg[c][(r + ky) * 19 + cl + kx];
#pragma unroll
        for (int e = 0; e < 32; ++e)
#pragma unroll
            for (int k = 0; k < 9; ++k)
                acc[e] += t[k] * kw1[(e * 64 + c) * 9 + k];
    }
    // f half (channels 32..63), 2x2-replicated fs via lowres indices
    int lr[3], lc[3];
#pragma unroll
    for (int d = 0; d < 3; ++d) {
        lr[d] = ((y + d - 1) >> 1) - ly0;   // arithmetic shift: -1>>1 = -1 -> row 0 (zeroed)
        lc[d] = ((x + d - 1) >> 1) - lx0;
    }
#pragma unroll 1
    for (int c = 0; c < 32; ++c) {
        float t[9];
#pragma unroll
        for (int ky = 0; ky < 3; ++ky)
#pragma unroll
            for (int kx = 0; kx < 3; ++kx)
                t[ky * 3 + kx] = smf[c][lr[ky] * 11 + lc[kx]];
#pragma unroll
        for (int e = 0; e < 32; ++e)
#pragma unroll
            for (int k = 0; k < 9; ++k)
                acc[e] += t[k] * kw1[(e * 64 + 32 + c) * 9 + k];
    }
    // ReLU -> 1x1 head -> softmax
    float z[9];
#pragma unroll
    for (int i = 0; i < 9; ++i) z[i] = kb2[i];
#pragma unroll
    for (int e = 0; e < 32; ++e) {
        float ae = fmaxf(acc[e], 0.f);
#pragma unroll
        for (int i = 0; i < 9; ++i)
            z[i] += ae * kw2[i * 32 + e];
    }
    float m = z[0];
#pragma unroll
    for (int i = 1; i < 9; ++i) m = fmaxf(m, z[i]);
    float sum = 0.f;
#pragma unroll
    for (int i = 0; i < 9; ++i) { z[i] = expf(z[i] - m); sum += z[i]; }
    float inv = 1.f / sum;
#pragma unroll
    for (int i = 0; i < 9; ++i)
        kern[((b * 9 + i) * 256 + y) * 256 + x] = z[i] * inv;
}

// ---- CARAFE reassembly, LDS-tiled, 32-channel chunks -------------------
__global__ __launch_bounds__(256) void k_out_t(
    const float* __restrict__ feat, const float* __restrict__ kern,
    float* __restrict__ out)
{
    __shared__ float sm[32][342];    // 43.8 KB feat chunk tile
    int tid = threadIdx.x;
    int blk = blockIdx.x;            // b*256 + chunk*64 + tile
    int b = blk >> 8;
    int chunk = (blk >> 6) & 3;
    int tile = blk & 63;             // 8x8 tiles over 128x128 lowres
    int ty0 = (tile >> 3) << 4, tx0 = (tile & 7) << 4;

    for (int i = tid; i < 10368; i += 256) {
        int j = i / 324;
        int rem = i - j * 324;
        int r = rem / 18, cl = rem - r * 18;
        int yy = ty0 + r - 1, xx = tx0 + cl - 1;
        int c = chunk * 32 + j;
        float v = 0.f;
        if (yy >= 0 && yy < 128 && xx >= 0 && xx < 128)
            v = feat[((b * 128 + c) * 128 + yy) * 128 + xx];
        sm[j][r * 19 + cl] = v;
    }
    __syncthreads();

    int r = tid >> 4, cl = tid & 15;
    int y = ty0 + r, x = tx0 + cl;

    float k4[2][2][9];
#pragma unroll
    for (int i = 0; i < 9; ++i)
#pragma unroll
        for (int ry = 0; ry < 2; ++ry) {
            const float2 kv = *reinterpret_cast<const float2*>(
                &kern[(((b * 9 + i) * 256) + (2 * y + ry)) * 256 + 2 * x]);
            k4[ry][0][i] = kv.x;
            k4[ry][1][i] = kv.y;
        }
    const int jmap[2][3] = { {0, 1, 1}, {1, 1, 2} };

#pragma unroll 1
    for (int j = 0; j < 32; ++j) {
        int c = chunk * 32 + j;
        float f3[3][3];
#pragma unroll
        for (int jy = 0; jy < 3; ++jy)
#pragma unroll
            for (int jx = 0; jx < 3; ++jx)
                f3[jy][jx] = sm[j][(r + jy) * 19 + cl + jx];
        float a[2][2] = { {0.f, 0.f}, {0.f, 0.f} };
#pragma unroll
        for (int ry = 0; ry < 2; ++ry)
#pragma unroll
            for (int dy = 0; dy < 3; ++dy)
#pragma unroll
                for (int rx = 0; rx < 2; ++rx)
#pragma unroll
                    for (int dx = 0; dx < 3; ++dx)
                        a[ry][rx] += k4[ry][rx][dy * 3 + dx] * f3[jmap[ry][dy]][jmap[rx][dx]];
#pragma unroll
        for (int ry = 0; ry < 2; ++ry) {
            float2 o; o.x = a[ry][0]; o.y = a[ry][1];
            *reinterpret_cast<float2*>(
                &out[((b * 128 + c) * 256 + (2 * y + ry)) * 256 + 2 * x]) = o;
        }
    }
}

extern "C" void kernel_launch(void* const* d_in, const int* in_sizes, int n_in,
                              void* d_out, int out_size, void* d_ws, size_t ws_size,
                              hipStream_t stream)
{
    const float* feat  = (const float*)d_in[0];
    const float* guide = (const float*)d_in[1];
    const float* g_w1  = (const float*)d_in[2];
    const float* g_g1  = (const float*)d_in[3];
    const float* g_b1  = (const float*)d_in[4];
    const float* g_w2  = (const float*)d_in[5];
    const float* g_g2  = (const float*)d_in[6];
    const float* g_b2  = (const float*)d_in[7];
    const float* p_w   = (const float*)d_in[8];
    const float* k_w1  = (const float*)d_in[9];
    const float* k_w2  = (const float*)d_in[10];
    const float* k_b2  = (const float*)d_in[11];

    float* out = (float*)d_out;

    // Big intermediates live inside d_out (64 MB), dead before k_out writes it.
    float* x1 = out;                  // 2*32*256*256 floats
    float* x2 = out + 4194304;

    float* fs   = (float*)d_ws;       // 2,097,152 floats
    float* kern = fs + 2097152;       // 1,179,648 floats
    float* ab1  = kern + 1179648;     // 64 floats
    float* ab2  = ab1 + 64;           // 64 floats

    k_conv1_t<<<512, 256, 0, stream>>>(guide, g_w1, x1);
    k_stats<<<32, 256, 0, stream>>>(x1, g_g1, g_b1, ab1);
    k_conv2_t<<<512, 256, 0, stream>>>(x1, ab1, g_w2, x2);
    k_stats<<<32, 256, 0, stream>>>(x2, g_g2, g_b2, ab2);
    k_proj2<<<512, 256, 0, stream>>>(feat, p_w, fs);
    k_kern_t<<<512, 256, 0, stream>>>(x2, ab2, fs, k_w1, k_w2, k_b2, kern);
    k_out_t<<<512, 256, 0, stream>>>(feat, kern, out);
}

// Round 5
// 124.776 us; speedup vs baseline: 5.3035x; 5.3035x over previous
//
#include <hip/hip_runtime.h>

#define EPS 1e-5f

// dims: feat (2,128,128,128) f32 NCHW, guide (2,3,256,256) f32 NCHW,
// out (2,128,256,256) f32 NCHW. E=32, K=3, k2=9. H2=W2=256.
// Intermediates: x1,x2 bf16 NHWC (2,256,256,32) in d_out; fs bf16 NHWC
// (2,128,128,32), kern12 f32 [px][12] NHWC-padded, packed weights in d_ws.

typedef unsigned short ushort_t;
typedef __attribute__((ext_vector_type(8))) short short8v;   // 8 bf16 = 4 VGPR
typedef __attribute__((ext_vector_type(4))) float f32x4;

__device__ __forceinline__ int swz(int b) { return b ^ (((b >> 7) & 7) << 4); }
__device__ __forceinline__ float bf2f(ushort_t u) {
    unsigned int t = ((unsigned int)u) << 16;
    return __builtin_bit_cast(float, t);
}
__device__ __forceinline__ ushort_t f2bf(float f) {   // RNE
    unsigned int x = __builtin_bit_cast(unsigned int, f);
    unsigned int r = (x + 0x7FFFu + ((x >> 16) & 1u)) >> 16;
    return (ushort_t)r;
}

// ---- weight prep: pack w2 and kw1 into B-fragment order, bf16 ----------
// w2pk  [t][nt][l][j]      : 9*2*64*8  = 9216  bf16
// kw1pk [t][kk][nt][l][j]  : 9*2*2*64*8 = 18432 bf16
__global__ __launch_bounds__(256) void k_prep(
    const float* __restrict__ w2, const float* __restrict__ kw1,
    ushort_t* __restrict__ wpk)
{
    int i = blockIdx.x * 256 + threadIdx.x;
    if (i < 9216) {
        int j = i & 7, l = (i >> 3) & 63, nt = (i >> 9) & 1, t = i >> 10;
        int e = nt * 16 + (l & 15);
        int k = (l >> 4) * 8 + j;
        wpk[i] = f2bf(w2[(e * 32 + k) * 9 + t]);
    } else if (i < 9216 + 18432) {
        int i2 = i - 9216;
        int j = i2 & 7, l = (i2 >> 3) & 63, nt = (i2 >> 9) & 1;
        int kk = (i2 >> 10) & 1, t = i2 >> 11;
        int e = nt * 16 + (l & 15);
        int k = kk * 32 + (l >> 4) * 8 + j;
        wpk[i] = f2bf(kw1[(e * 64 + k) * 9 + t]);
    }
}

// ---- conv1: guide 3->32, LDS-tiled, out bf16 NHWC ----------------------
__global__ __launch_bounds__(256) void k_conv1(
    const float* __restrict__ guide, const float* __restrict__ w1,
    ushort_t* __restrict__ x1)
{
    __shared__ float sm[3][342];           // 18 rows * stride 19
    int tid = threadIdx.x;
    int b = blockIdx.x >> 8;
    int tile = blockIdx.x & 255;
    int ty0 = (tile >> 4) << 4, tx0 = (tile & 15) << 4;

    for (int i = tid; i < 972; i += 256) {
        int c = i / 324;
        int rem = i - c * 324;
        int r = rem / 18, cl = rem - r * 18;
        int yy = ty0 + r - 1, xx = tx0 + cl - 1;
        float v = 0.f;
        if (yy >= 0 && yy < 256 && xx >= 0 && xx < 256)
            v = guide[((b * 3 + c) * 256 + yy) * 256 + xx];
        sm[c][r * 19 + cl] = v;
    }
    __syncthreads();

    int r = tid >> 4, cl = tid & 15;
    float t[27];
#pragma unroll
    for (int c = 0; c < 3; ++c)
#pragma unroll
        for (int ky = 0; ky < 3; ++ky)
#pragma unroll
            for (int kx = 0; kx < 3; ++kx)
                t[c * 9 + ky * 3 + kx] = sm[c][(r + ky) * 19 + cl + kx];
    int y = ty0 + r, x = tx0 + cl;
    ushort_t pk[32];
#pragma unroll 4
    for (int e = 0; e < 32; ++e) {
        float acc = 0.f;
#pragma unroll
        for (int k = 0; k < 27; ++k)
            acc += t[k] * w1[e * 27 + k];
        pk[e] = f2bf(acc);
    }
    ushort_t* dst = x1 + ((size_t)(b * 65536 + y * 256 + x)) * 32;
#pragma unroll
    for (int h = 0; h < 4; ++h)
        *(uint4*)(dst + h * 8) = *(uint4*)(pk + h * 8);
}

// ---- stats partial: bf16 NHWC (2*65536 px, 32 ch) -> part[64][64] ------
__global__ __launch_bounds__(256) void k_statsP(
    const ushort_t* __restrict__ x, float* __restrict__ part)
{
    int tid = threadIdx.x, bk = blockIdx.x;
    int p = tid >> 4, c2 = tid & 15;
    float s0 = 0.f, ss0 = 0.f, s1 = 0.f, ss1 = 0.f;
    const ushort_t* base = x + ((size_t)bk * 2048) * 32 + c2 * 2;
    for (int i = 0; i < 128; ++i) {
        unsigned int v = *(const unsigned int*)(base + (size_t)(i * 16 + p) * 32);
        float a = bf2f((ushort_t)(v & 0xffff));
        float c = bf2f((ushort_t)(v >> 16));
        s0 += a; ss0 += a * a; s1 += c; ss1 += c * c;
    }
    __shared__ float red[256][4];
    red[tid][0] = s0; red[tid][1] = ss0; red[tid][2] = s1; red[tid][3] = ss1;
    __syncthreads();
    if (tid < 64) {
        int c2s = tid & 15, vs = tid >> 4;
        float t = 0.f;
        for (int pp = 0; pp < 16; ++pp) t += red[pp * 16 + c2s][vs];
        part[bk * 64 + c2s * 4 + vs] = t;
    }
}

__global__ void k_statsF(
    const float* __restrict__ part, const float* __restrict__ gamma,
    const float* __restrict__ beta, float* __restrict__ ab)
{
    __shared__ float tot[64];
    int t = threadIdx.x;     // 64 threads
    float s = 0.f;
    for (int bk = 0; bk < 64; ++bk) s += part[bk * 64 + t];
    tot[t] = s;
    __syncthreads();
    if (t < 32) {
        int c = t;
        float S  = tot[(c >> 1) * 4 + (c & 1) * 2];
        float SS = tot[(c >> 1) * 4 + (c & 1) * 2 + 1];
        const float n = 131072.f;
        float mean = S / n;
        float var = SS / n - mean * mean;
        float a = gamma[c] * rsqrtf(var + EPS);
        ab[c] = a;
        ab[32 + c] = beta[c] - mean * a;
    }
}

// ---- conv2: bnrelu(x1) 32->32, bf16 MFMA implicit GEMM -----------------
__global__ __launch_bounds__(256) void k_conv2_m(
    const ushort_t* __restrict__ x1, const float* __restrict__ ab1,
    const ushort_t* __restrict__ w2pk, ushort_t* __restrict__ x2)
{
    __shared__ __align__(16) char lds[20736];   // At: 324 px * 32 ch bf16
    int tid = threadIdx.x;
    int b = blockIdx.x >> 8, tile = blockIdx.x & 255;
    int ty0 = (tile >> 4) << 4, tx0 = (tile & 15) << 4;

    // stage A tile (bnrelu fused), 324 px * 4 chunks of 8 ch
    for (int i = tid; i < 1296; i += 256) {
        int px = i >> 2, c8 = i & 3;
        int r = px / 18, cl = px - r * 18;
        int yy = ty0 + r - 1, xx = tx0 + cl - 1;
        ushort_t pk[8];
        if (yy >= 0 && yy < 256 && xx >= 0 && xx < 256) {
            const ushort_t* src = x1 + ((size_t)(b * 65536 + yy * 256 + xx)) * 32 + c8 * 8;
            uint4 raw = *(const uint4*)src;
            const ushort_t* rs = (const ushort_t*)&raw;
#pragma unroll
            for (int j = 0; j < 8; ++j) {
                int c = c8 * 8 + j;
                pk[j] = f2bf(fmaxf(ab1[c] * bf2f(rs[j]) + ab1[32 + c], 0.f));
            }
        } else {
#pragma unroll
            for (int j = 0; j < 8; ++j) pk[j] = 0;
        }
        *(uint4*)(lds + swz(px * 64 + c8 * 16)) = *(uint4*)pk;
    }
    __syncthreads();

    int w = tid >> 6, l = tid & 63, lm = l & 15, lg = l >> 4;
    f32x4 acc[4][2] = {};
    const short8v* gB = (const short8v*)w2pk;
#pragma unroll
    for (int t = 0; t < 9; ++t) {
        int ky = t / 3, kx = t % 3;
        short8v B0 = gB[(t * 2 + 0) * 64 + l];
        short8v B1 = gB[(t * 2 + 1) * 64 + l];
#pragma unroll
        for (int m = 0; m < 4; ++m) {
            int px = (w * 4 + m + ky) * 18 + lm + kx;
            short8v A = *(const short8v*)(lds + swz(px * 64 + lg * 16));
            acc[m][0] = __builtin_amdgcn_mfma_f32_16x16x32_bf16(A, B0, acc[m][0], 0, 0, 0);
            acc[m][1] = __builtin_amdgcn_mfma_f32_16x16x32_bf16(A, B1, acc[m][1], 0, 0, 0);
        }
    }
    // epilogue: dump to LDS (bf16 [px][32]) then coalesced global write
    __syncthreads();
#pragma unroll
    for (int m = 0; m < 4; ++m)
#pragma unroll
        for (int nt = 0; nt < 2; ++nt)
#pragma unroll
            for (int rg = 0; rg < 4; ++rg) {
                int px = (w * 4 + m) * 16 + lg * 4 + rg;
                int e = nt * 16 + lm;
                *(ushort_t*)(lds + swz(px * 64 + e * 2)) = f2bf(acc[m][nt][rg]);
            }
    __syncthreads();
    {
        int px = tid, r = px >> 4, cl = px & 15;
        int yy = ty0 + r, xx = tx0 + cl;
        ushort_t* dst = x2 + ((size_t)(b * 65536 + yy * 256 + xx)) * 32;
#pragma unroll
        for (int h = 0; h < 4; ++h)
            *(uint4*)(dst + h * 8) = *(uint4*)(lds + swz(px * 64 + h * 16));
    }
}

// ---- 1x1 proj at lowres -> fs bf16 NHWC --------------------------------
__global__ __launch_bounds__(256) void k_proj(
    const float* __restrict__ feat, const float* __restrict__ pw,
    ushort_t* __restrict__ fs)
{
    __shared__ float sm[32 * 65];
    int tid = threadIdx.x;
    unsigned pix0 = blockIdx.x * 64u;
    int p = tid & 63, q = tid >> 6;
    unsigned pix = pix0 + p;
    int x = pix & 127, y = (pix >> 7) & 127, b = pix >> 14;
    float acc[8];
#pragma unroll
    for (int e = 0; e < 8; ++e) acc[e] = 0.f;
    const float* fb = feat + ((size_t)b << 21) + y * 128 + x;
#pragma unroll 4
    for (int c = 0; c < 128; ++c) {
        float v = fb[(size_t)c << 14];
#pragma unroll
        for (int e = 0; e < 8; ++e)
            acc[e] += v * pw[(q * 8 + e) * 128 + c];
    }
#pragma unroll
    for (int e = 0; e < 8; ++e)
        sm[(q * 8 + e) * 65 + p] = fmaxf(acc[e], 0.f);
    __syncthreads();
    {
        int px = tid >> 2, c8 = tid & 3;
        ushort_t pk[8];
#pragma unroll
        for (int j = 0; j < 8; ++j) pk[j] = f2bf(sm[(c8 * 8 + j) * 65 + px]);
        unsigned gp = pix0 + px;
        *(uint4*)(fs + (size_t)gp * 32 + c8 * 8) = *(uint4*)pk;
    }
}

// ---- kernel head: conv3x3 64->32 (MFMA) + ReLU + 1x1->9 + softmax ------
__global__ __launch_bounds__(256) void k_kern_m(
    const ushort_t* __restrict__ x2, const float* __restrict__ ab2,
    const ushort_t* __restrict__ fs, const ushort_t* __restrict__ kw1pk,
    const float* __restrict__ kw2, const float* __restrict__ kb2,
    float* __restrict__ kern12)
{
    __shared__ __align__(16) char lds[41472];   // comb: 324 px * 64 ch bf16
    int tid = threadIdx.x;
    int b = blockIdx.x >> 8, tile = blockIdx.x & 255;
    int ty0 = (tile >> 4) << 4, tx0 = (tile & 15) << 4;

    // stage comb tile: g (ch 0..31) = bnrelu(x2), f (ch 32..63) = fs repl.
    for (int i = tid; i < 2592; i += 256) {     // 324 px * 8 chunks
        int px = i >> 3, c8 = i & 7;
        int r = px / 18, cl = px - r * 18;
        int yy = ty0 + r - 1, xx = tx0 + cl - 1;
        ushort_t pk[8];
        if (yy >= 0 && yy < 256 && xx >= 0 && xx < 256) {
            if (c8 < 4) {
                const ushort_t* src = x2 + ((size_t)(b * 65536 + yy * 256 + xx)) * 32 + c8 * 8;
                uint4 raw = *(const uint4*)src;
                const ushort_t* rs = (const ushort_t*)&raw;
#pragma unroll
                for (int j = 0; j < 8; ++j) {
                    int c = c8 * 8 + j;
                    pk[j] = f2bf(fmaxf(ab2[c] * bf2f(rs[j]) + ab2[32 + c], 0.f));
                }
            } else {
                const ushort_t* src = fs + ((size_t)(b * 16384 + (yy >> 1) * 128 + (xx >> 1))) * 32 + (c8 - 4) * 8;
                *(uint4*)pk = *(const uint4*)src;
            }
        } else {
#pragma unroll
            for (int j = 0; j < 8; ++j) pk[j] = 0;
        }
        *(uint4*)(lds + swz(px * 128 + c8 * 16)) = *(uint4*)pk;
    }
    __syncthreads();

    int w = tid >> 6, l = tid & 63, lm = l & 15, lg = l >> 4;
    f32x4 acc[4][2] = {};
    const short8v* gB = (const short8v*)kw1pk;
#pragma unroll
    for (int t = 0; t < 9; ++t) {
        int ky = t / 3, kx = t % 3;
#pragma unroll
        for (int kk = 0; kk < 2; ++kk) {
            short8v B0 = gB[(t * 4 + kk * 2 + 0) * 64 + l];
            short8v B1 = gB[(t * 4 + kk * 2 + 1) * 64 + l];
#pragma unroll
            for (int m = 0; m < 4; ++m) {
                int px = (w * 4 + m + ky) * 18 + lm + kx;
                short8v A = *(const short8v*)(lds + swz(px * 128 + kk * 64 + lg * 16));
                acc[m][0] = __builtin_amdgcn_mfma_f32_16x16x32_bf16(A, B0, acc[m][0], 0, 0, 0);
                acc[m][1] = __builtin_amdgcn_mfma_f32_16x16x32_bf16(A, B1, acc[m][1], 0, 0, 0);
            }
        }
    }
    // dump conv outputs (pre-relu) to LDS fp32 [px][32]
    __syncthreads();
#pragma unroll
    for (int m = 0; m < 4; ++m)
#pragma unroll
        for (int nt = 0; nt < 2; ++nt)
#pragma unroll
            for (int rg = 0; rg < 4; ++rg) {
                int px = (w * 4 + m) * 16 + lg * 4 + rg;
                int e = nt * 16 + lm;
                *(float*)(lds + swz(px * 128 + e * 4)) = acc[m][nt][rg];
            }
    __syncthreads();
    // per-pixel head: ReLU -> 1x1 -> softmax -> kern12
    {
        int px = tid, r = px >> 4, cl = px & 15;
        float v[32];
#pragma unroll
        for (int h = 0; h < 8; ++h) {
            float4 q = *(const float4*)(lds + swz(px * 128 + h * 16));
            v[h * 4 + 0] = q.x; v[h * 4 + 1] = q.y; v[h * 4 + 2] = q.z; v[h * 4 + 3] = q.w;
        }
        float z[9];
#pragma unroll
        for (int i = 0; i < 9; ++i) z[i] = kb2[i];
#pragma unroll
        for (int e = 0; e < 32; ++e) {
            float ae = fmaxf(v[e], 0.f);
#pragma unroll
            for (int i = 0; i < 9; ++i)
                z[i] += ae * kw2[i * 32 + e];
        }
        float m = z[0];
#pragma unroll
        for (int i = 1; i < 9; ++i) m = fmaxf(m, z[i]);
        float sum = 0.f;
#pragma unroll
        for (int i = 0; i < 9; ++i) { z[i] = expf(z[i] - m); sum += z[i]; }
        float inv = 1.f / sum;
#pragma unroll
        for (int i = 0; i < 9; ++i) z[i] *= inv;
        size_t gp = (size_t)(b * 65536 + (ty0 + r) * 256 + (tx0 + cl));
        float4* dp = (float4*)(kern12 + gp * 12);
        float4 o0, o1, o2;
        o0.x = z[0]; o0.y = z[1]; o0.z = z[2]; o0.w = z[3];
        o1.x = z[4]; o1.y = z[5]; o1.z = z[6]; o1.w = z[7];
        o2.x = z[8]; o2.y = 0.f;  o2.z = 0.f;  o2.w = 0.f;
        dp[0] = o0; dp[1] = o1; dp[2] = o2;
    }
}

// ---- CARAFE reassembly: 8-ch chunks, replication-collapsed taps --------
__global__ __launch_bounds__(256) void k_out2(
    const float* __restrict__ feat, const float* __restrict__ kern12,
    float* __restrict__ out)
{
    __shared__ __align__(16) char smf[10368];   // 324 px * 8 ch fp32
    int tid = threadIdx.x;
    int blk = blockIdx.x;                 // 2048 = b(2) * chunk(16) * tile(64)
    int b = blk >> 10;
    int chunk = (blk >> 6) & 15;
    int tile = blk & 63;
    int ty0 = (tile >> 3) << 4, tx0 = (tile & 7) << 4;

    for (int i = tid; i < 648; i += 256) {
        int c4 = i / 324, px = i - c4 * 324;
        int r = px / 18, cl = px - r * 18;
        int yy = ty0 + r - 1, xx = tx0 + cl - 1;
        float4 v; v.x = 0.f; v.y = 0.f; v.z = 0.f; v.w = 0.f;
        if (yy >= 0 && yy < 128 && xx >= 0 && xx < 128) {
            int c0 = chunk * 8 + c4 * 4;
            size_t base = ((size_t)(b * 128 + c0) << 14) + yy * 128 + xx;
            v.x = feat[base];
            v.y = feat[base + (1 << 14)];
            v.z = feat[base + (2 << 14)];
            v.w = feat[base + (3 << 14)];
        }
        *(float4*)(smf + swz(px * 32 + c4 * 16)) = v;
    }
    __syncthreads();

    int r = tid >> 4, cl = tid & 15;
    int y = ty0 + r, x = tx0 + cl;

    float k4[2][2][9];
#pragma unroll
    for (int ry = 0; ry < 2; ++ry)
#pragma unroll
        for (int rx = 0; rx < 2; ++rx) {
            // FIX (round 5): batch offset was missing -> batch 1 used batch 0's kern
            size_t hp = (size_t)(b * 65536 + (2 * y + ry) * 256 + (2 * x + rx));
            const float4* kp = (const float4*)(kern12 + hp * 12);
            float4 q0 = kp[0], q1 = kp[1], q2 = kp[2];
            k4[ry][rx][0] = q0.x; k4[ry][rx][1] = q0.y; k4[ry][rx][2] = q0.z;
            k4[ry][rx][3] = q0.w; k4[ry][rx][4] = q1.x; k4[ry][rx][5] = q1.y;
            k4[ry][rx][6] = q1.z; k4[ry][rx][7] = q1.w; k4[ry][rx][8] = q2.x;
        }

    const int jmap[2][3] = { {0, 1, 1}, {1, 1, 2} };
    float acc[8][4];
#pragma unroll
    for (int ch = 0; ch < 8; ++ch)
#pragma unroll
        for (int o = 0; o < 4; ++o) acc[ch][o] = 0.f;

#pragma unroll
    for (int ny = 0; ny < 3; ++ny)
#pragma unroll
        for (int nx = 0; nx < 3; ++nx) {
            float co[2][2];
#pragma unroll
            for (int ry = 0; ry < 2; ++ry)
#pragma unroll
                for (int rx = 0; rx < 2; ++rx) {
                    float s = 0.f;
#pragma unroll
                    for (int a = 0; a < 3; ++a)
#pragma unroll
                        for (int bq = 0; bq < 3; ++bq)
                            if (jmap[ry][a] == ny && jmap[rx][bq] == nx)
                                s += k4[ry][rx][a * 3 + bq];
                    co[ry][rx] = s;
                }
            int px = (r + ny) * 18 + cl + nx;
            float4 f0 = *(const float4*)(smf + swz(px * 32));
            float4 f1 = *(const float4*)(smf + swz(px * 32 + 16));
            float fv[8] = { f0.x, f0.y, f0.z, f0.w, f1.x, f1.y, f1.z, f1.w };
#pragma unroll
            for (int ch = 0; ch < 8; ++ch) {
                acc[ch][0] += co[0][0] * fv[ch];
                acc[ch][1] += co[0][1] * fv[ch];
                acc[ch][2] += co[1][0] * fv[ch];
                acc[ch][3] += co[1][1] * fv[ch];
            }
        }

#pragma unroll
    for (int ch = 0; ch < 8; ++ch) {
        int c = chunk * 8 + ch;
        size_t base = (((size_t)(b * 128 + c) * 256 + 2 * y) * 256 + 2 * x);
        float2 o0, o1;
        o0.x = acc[ch][0]; o0.y = acc[ch][1];
        o1.x = acc[ch][2]; o1.y = acc[ch][3];
        *(float2*)(out + base) = o0;
        *(float2*)(out + base + 256) = o1;
    }
}

extern "C" void kernel_launch(void* const* d_in, const int* in_sizes, int n_in,
                              void* d_out, int out_size, void* d_ws, size_t ws_size,
                              hipStream_t stream)
{
    const float* feat  = (const float*)d_in[0];
    const float* guide = (const float*)d_in[1];
    const float* g_w1  = (const float*)d_in[2];
    const float* g_g1  = (const float*)d_in[3];
    const float* g_b1  = (const float*)d_in[4];
    const float* g_w2  = (const float*)d_in[5];
    const float* g_g2  = (const float*)d_in[6];
    const float* g_b2  = (const float*)d_in[7];
    const float* p_w   = (const float*)d_in[8];
    const float* k_w1  = (const float*)d_in[9];
    const float* k_w2  = (const float*)d_in[10];
    const float* k_b2  = (const float*)d_in[11];

    float* out = (float*)d_out;

    // bf16 NHWC intermediates inside d_out (dead before k_out2 writes):
    ushort_t* x1 = (ushort_t*)out;                    // 4,194,304 bf16 = 8.4MB
    ushort_t* x2 = (ushort_t*)(out + 2097152);        // 4,194,304 bf16

    // workspace layout
    float*    kern12 = (float*)d_ws;                  // 1,572,864 f32 (6.3MB)
    ushort_t* fs     = (ushort_t*)((char*)d_ws + 6291456);   // 1,048,576 bf16
    ushort_t* wpk    = (ushort_t*)((char*)d_ws + 8388608);   // 27,648 bf16
    float*    part   = (float*)((char*)d_ws + 8444928);      // 4096 f32
    float*    ab1    = (float*)((char*)d_ws + 8461312);      // 64 f32
    float*    ab2    = (float*)((char*)d_ws + 8461568);      // 64 f32
    ushort_t* w2pk   = wpk;
    ushort_t* kw1pk  = wpk + 9216;

    k_prep<<<108, 256, 0, stream>>>(g_w2, k_w1, wpk);
    k_conv1<<<512, 256, 0, stream>>>(guide, g_w1, x1);
    k_statsP<<<64, 256, 0, stream>>>(x1, part);
    k_statsF<<<1, 64, 0, stream>>>(part, g_g1, g_b1, ab1);
    k_conv2_m<<<512, 256, 0, stream>>>(x1, ab1, w2pk, x2);
    k_statsP<<<64, 256, 0, stream>>>(x2, part);
    k_statsF<<<1, 64, 0, stream>>>(part, g_g2, g_b2, ab2);
    k_proj<<<512, 256, 0, stream>>>(feat, p_w, fs);
    k_kern_m<<<512, 256, 0, stream>>>(x2, ab2, fs, kw1pk, k_w2, k_b2, kern12);
    k_out2<<<2048, 256, 0, stream>>>(feat, kern12, out);
}

// Round 6
// 107.965 us; speedup vs baseline: 6.1293x; 1.1557x over previous
//
#include <hip/hip_runtime.h>
#include <hip/hip_bf16.h>

#define EPS 1e-5f

// dims: feat (2,128,128,128) f32 NCHW, guide (2,3,256,256) f32 NCHW,
// out (2,128,256,256) f32 NCHW. E=32, K=3, k2=9. H2=W2=256.
// x1,x2 bf16 NHWC (2,256,256,32) in d_out; fs bf16 NHWC (2,128,128,32),
// kern48 f32 [lowres px][4 subpx][12], packed weights, stats in d_ws.

typedef unsigned short ushort_t;
typedef __attribute__((ext_vector_type(8))) short short8v;   // 8 bf16 = 4 VGPR
typedef __attribute__((ext_vector_type(4))) float f32x4;

__device__ __forceinline__ int swz(int b) { return b ^ (((b >> 7) & 7) << 4); }
__device__ __forceinline__ float bf2f(ushort_t u) {
    unsigned int t = ((unsigned int)u) << 16;
    return __builtin_bit_cast(float, t);
}
__device__ __forceinline__ ushort_t f2bf(float f) {   // RNE via HW cvt
    __hip_bfloat16 h = (__hip_bfloat16)f;
    return __builtin_bit_cast(ushort_t, h);
}

// ---- phase 1: prep (wpk), conv1 (guide->x1), proj (feat->fs) -----------
// grid: [0,512) conv1 | [512,1024) proj | [1024,1132) prep
__global__ __launch_bounds__(256) void k_phase1(
    const float* __restrict__ guide, const float* __restrict__ w1,
    const float* __restrict__ feat, const float* __restrict__ pw,
    const float* __restrict__ w2, const float* __restrict__ kw1,
    ushort_t* __restrict__ x1, ushort_t* __restrict__ fs,
    ushort_t* __restrict__ wpk)
{
    __shared__ float smu[2080];
    int tid = threadIdx.x;
    int blk = blockIdx.x;

    if (blk < 512) {
        // ---- conv1: guide 3->32, LDS-tiled, out bf16 NHWC ----
        int b = blk >> 8;
        int tile = blk & 255;
        int ty0 = (tile >> 4) << 4, tx0 = (tile & 15) << 4;

        for (int i = tid; i < 972; i += 256) {
            int c = i / 324;
            int rem = i - c * 324;
            int r = rem / 18, cl = rem - r * 18;
            int yy = ty0 + r - 1, xx = tx0 + cl - 1;
            float v = 0.f;
            if (yy >= 0 && yy < 256 && xx >= 0 && xx < 256)
                v = guide[((b * 3 + c) * 256 + yy) * 256 + xx];
            smu[c * 342 + r * 19 + cl] = v;
        }
        __syncthreads();

        int r = tid >> 4, cl = tid & 15;
        float t[27];
#pragma unroll
        for (int c = 0; c < 3; ++c)
#pragma unroll
            for (int ky = 0; ky < 3; ++ky)
#pragma unroll
                for (int kx = 0; kx < 3; ++kx)
                    t[c * 9 + ky * 3 + kx] = smu[c * 342 + (r + ky) * 19 + cl + kx];
        int y = ty0 + r, x = tx0 + cl;
        ushort_t pk[32];
#pragma unroll 4
        for (int e = 0; e < 32; ++e) {
            float acc = 0.f;
#pragma unroll
            for (int k = 0; k < 27; ++k)
                acc += t[k] * w1[e * 27 + k];
            pk[e] = f2bf(acc);
        }
        ushort_t* dst = x1 + ((size_t)(b * 65536 + y * 256 + x)) * 32;
#pragma unroll
        for (int h = 0; h < 4; ++h)
            *(uint4*)(dst + h * 8) = *(uint4*)(pk + h * 8);
    } else if (blk < 1024) {
        // ---- 1x1 proj at lowres -> fs bf16 NHWC ----
        unsigned pix0 = (blk - 512) * 64u;
        int p = tid & 63, q = tid >> 6;
        unsigned pix = pix0 + p;
        int x = pix & 127, y = (pix >> 7) & 127, b = pix >> 14;
        float acc[8];
#pragma unroll
        for (int e = 0; e < 8; ++e) acc[e] = 0.f;
        const float* fb = feat + ((size_t)b << 21) + y * 128 + x;
#pragma unroll 4
        for (int c = 0; c < 128; ++c) {
            float v = fb[(size_t)c << 14];
#pragma unroll
            for (int e = 0; e < 8; ++e)
                acc[e] += v * pw[(q * 8 + e) * 128 + c];
        }
#pragma unroll
        for (int e = 0; e < 8; ++e)
            smu[(q * 8 + e) * 65 + p] = fmaxf(acc[e], 0.f);
        __syncthreads();
        {
            int px = tid >> 2, c8 = tid & 3;
            ushort_t pk[8];
#pragma unroll
            for (int j = 0; j < 8; ++j) pk[j] = f2bf(smu[(c8 * 8 + j) * 65 + px]);
            unsigned gp = pix0 + px;
            *(uint4*)(fs + (size_t)gp * 32 + c8 * 8) = *(uint4*)pk;
        }
    } else {
        // ---- weight prep: pack w2, kw1 into B-fragment order, bf16 ----
        int i = (blk - 1024) * 256 + tid;     // 0..27647
        if (i < 9216) {
            int j = i & 7, l = (i >> 3) & 63, nt = (i >> 9) & 1, t = i >> 10;
            int e = nt * 16 + (l & 15);
            int k = (l >> 4) * 8 + j;
            wpk[i] = f2bf(w2[(e * 32 + k) * 9 + t]);
        } else {
            int i2 = i - 9216;
            int j = i2 & 7, l = (i2 >> 3) & 63, nt = (i2 >> 9) & 1;
            int kk = (i2 >> 10) & 1, t = i2 >> 11;
            int e = nt * 16 + (l & 15);
            int k = kk * 32 + (l >> 4) * 8 + j;
            wpk[i] = f2bf(kw1[(e * 64 + k) * 9 + t]);
        }
    }
}

// ---- stats partial: 256 blocks x 512 px -> part[256][64] ---------------
__global__ __launch_bounds__(256) void k_statsP(
    const ushort_t* __restrict__ x, float* __restrict__ part)
{
    int tid = threadIdx.x, bk = blockIdx.x;
    int p = tid >> 4, c2 = tid & 15;
    float s0 = 0.f, ss0 = 0.f, s1 = 0.f, ss1 = 0.f;
    const ushort_t* base = x + ((size_t)bk * 512) * 32 + c2 * 2;
    for (int i = 0; i < 32; ++i) {
        unsigned int v = *(const unsigned int*)(base + (size_t)(i * 16 + p) * 32);
        float a = bf2f((ushort_t)(v & 0xffff));
        float c = bf2f((ushort_t)(v >> 16));
        s0 += a; ss0 += a * a; s1 += c; ss1 += c * c;
    }
    __shared__ float red[256][4];
    red[tid][0] = s0; red[tid][1] = ss0; red[tid][2] = s1; red[tid][3] = ss1;
    __syncthreads();
    if (tid < 64) {
        int c2s = tid & 15, vs = tid >> 4;
        float t = 0.f;
        for (int pp = 0; pp < 16; ++pp) t += red[pp * 16 + c2s][vs];
        part[bk * 64 + c2s * 4 + vs] = t;
    }
}

__global__ void k_statsF(
    const float* __restrict__ part, const float* __restrict__ gamma,
    const float* __restrict__ beta, float* __restrict__ ab)
{
    __shared__ float tot[64];
    int t = threadIdx.x;     // 64 threads
    float s = 0.f;
    for (int bk = 0; bk < 256; ++bk) s += part[bk * 64 + t];
    tot[t] = s;
    __syncthreads();
    if (t < 32) {
        int c = t;
        float S  = tot[(c >> 1) * 4 + (c & 1) * 2];
        float SS = tot[(c >> 1) * 4 + (c & 1) * 2 + 1];
        const float n = 131072.f;
        float mean = S / n;
        float var = SS / n - mean * mean;
        float a = gamma[c] * rsqrtf(var + EPS);
        ab[c] = a;
        ab[32 + c] = beta[c] - mean * a;
    }
}

// ---- conv2: bnrelu(x1) 32->32, bf16 MFMA implicit GEMM -----------------
__global__ __launch_bounds__(256) void k_conv2_m(
    const ushort_t* __restrict__ x1, const float* __restrict__ ab1,
    const ushort_t* __restrict__ w2pk, ushort_t* __restrict__ x2)
{
    __shared__ __align__(16) char lds[20736];   // At: 324 px * 32 ch bf16
    int tid = threadIdx.x;
    int b = blockIdx.x >> 8, tile = blockIdx.x & 255;
    int ty0 = (tile >> 4) << 4, tx0 = (tile & 15) << 4;

    for (int i = tid; i < 1296; i += 256) {
        int px = i >> 2, c8 = i & 3;
        int r = px / 18, cl = px - r * 18;
        int yy = ty0 + r - 1, xx = tx0 + cl - 1;
        ushort_t pk[8];
        if (yy >= 0 && yy < 256 && xx >= 0 && xx < 256) {
            const ushort_t* src = x1 + ((size_t)(b * 65536 + yy * 256 + xx)) * 32 + c8 * 8;
            uint4 raw = *(const uint4*)src;
            const ushort_t* rs = (const ushort_t*)&raw;
#pragma unroll
            for (int j = 0; j < 8; ++j) {
                int c = c8 * 8 + j;
                pk[j] = f2bf(fmaxf(ab1[c] * bf2f(rs[j]) + ab1[32 + c], 0.f));
            }
        } else {
#pragma unroll
            for (int j = 0; j < 8; ++j) pk[j] = 0;
        }
        *(uint4*)(lds + swz(px * 64 + c8 * 16)) = *(uint4*)pk;
    }
    __syncthreads();

    int w = tid >> 6, l = tid & 63, lm = l & 15, lg = l >> 4;
    f32x4 acc[4][2] = {};
    const short8v* gB = (const short8v*)w2pk;
#pragma unroll
    for (int t = 0; t < 9; ++t) {
        int ky = t / 3, kx = t % 3;
        short8v B0 = gB[(t * 2 + 0) * 64 + l];
        short8v B1 = gB[(t * 2 + 1) * 64 + l];
#pragma unroll
        for (int m = 0; m < 4; ++m) {
            int px = (w * 4 + m + ky) * 18 + lm + kx;
            short8v A = *(const short8v*)(lds + swz(px * 64 + lg * 16));
            acc[m][0] = __builtin_amdgcn_mfma_f32_16x16x32_bf16(A, B0, acc[m][0], 0, 0, 0);
            acc[m][1] = __builtin_amdgcn_mfma_f32_16x16x32_bf16(A, B1, acc[m][1], 0, 0, 0);
        }
    }
    __syncthreads();
#pragma unroll
    for (int m = 0; m < 4; ++m)
#pragma unroll
        for (int nt = 0; nt < 2; ++nt)
#pragma unroll
            for (int rg = 0; rg < 4; ++rg) {
                int px = (w * 4 + m) * 16 + lg * 4 + rg;
                int e = nt * 16 + lm;
                *(ushort_t*)(lds + swz(px * 64 + e * 2)) = f2bf(acc[m][nt][rg]);
            }
    __syncthreads();
    {
        int px = tid, r = px >> 4, cl = px & 15;
        int yy = ty0 + r, xx = tx0 + cl;
        ushort_t* dst = x2 + ((size_t)(b * 65536 + yy * 256 + xx)) * 32;
#pragma unroll
        for (int h = 0; h < 4; ++h)
            *(uint4*)(dst + h * 8) = *(uint4*)(lds + swz(px * 64 + h * 16));
    }
}

// ---- kernel head: conv3x3 64->32 (MFMA) + ReLU + 1x1->9 + softmax ------
// writes kern48: [b*16384 + ly*128 + lx][sub(=ry*2+rx)][12]
__global__ __launch_bounds__(256) void k_kern_m(
    const ushort_t* __restrict__ x2, const float* __restrict__ ab2,
    const ushort_t* __restrict__ fs, const ushort_t* __restrict__ kw1pk,
    const float* __restrict__ kw2, const float* __restrict__ kb2,
    float* __restrict__ kern48)
{
    __shared__ __align__(16) char lds[41472];   // comb: 324 px * 64 ch bf16
    int tid = threadIdx.x;
    int b = blockIdx.x >> 8, tile = blockIdx.x & 255;
    int ty0 = (tile >> 4) << 4, tx0 = (tile & 15) << 4;

    for (int i = tid; i < 2592; i += 256) {     // 324 px * 8 chunks
        int px = i >> 3, c8 = i & 7;
        int r = px / 18, cl = px - r * 18;
        int yy = ty0 + r - 1, xx = tx0 + cl - 1;
        ushort_t pk[8];
        if (yy >= 0 && yy < 256 && xx >= 0 && xx < 256) {
            if (c8 < 4) {
                const ushort_t* src = x2 + ((size_t)(b * 65536 + yy * 256 + xx)) * 32 + c8 * 8;
                uint4 raw = *(const uint4*)src;
                const ushort_t* rs = (const ushort_t*)&raw;
#pragma unroll
                for (int j = 0; j < 8; ++j) {
                    int c = c8 * 8 + j;
                    pk[j] = f2bf(fmaxf(ab2[c] * bf2f(rs[j]) + ab2[32 + c], 0.f));
                }
            } else {
                const ushort_t* src = fs + ((size_t)(b * 16384 + (yy >> 1) * 128 + (xx >> 1))) * 32 + (c8 - 4) * 8;
                *(uint4*)pk = *(const uint4*)src;
            }
        } else {
#pragma unroll
            for (int j = 0; j < 8; ++j) pk[j] = 0;
        }
        *(uint4*)(lds + swz(px * 128 + c8 * 16)) = *(uint4*)pk;
    }
    __syncthreads();

    int w = tid >> 6, l = tid & 63, lm = l & 15, lg = l >> 4;
    f32x4 acc[4][2] = {};
    const short8v* gB = (const short8v*)kw1pk;
#pragma unroll
    for (int t = 0; t < 9; ++t) {
        int ky = t / 3, kx = t % 3;
#pragma unroll
        for (int kk = 0; kk < 2; ++kk) {
            short8v B0 = gB[(t * 4 + kk * 2 + 0) * 64 + l];
            short8v B1 = gB[(t * 4 + kk * 2 + 1) * 64 + l];
#pragma unroll
            for (int m = 0; m < 4; ++m) {
                int px = (w * 4 + m + ky) * 18 + lm + kx;
                short8v A = *(const short8v*)(lds + swz(px * 128 + kk * 64 + lg * 16));
                acc[m][0] = __builtin_amdgcn_mfma_f32_16x16x32_bf16(A, B0, acc[m][0], 0, 0, 0);
                acc[m][1] = __builtin_amdgcn_mfma_f32_16x16x32_bf16(A, B1, acc[m][1], 0, 0, 0);
            }
        }
    }
    __syncthreads();
#pragma unroll
    for (int m = 0; m < 4; ++m)
#pragma unroll
        for (int nt = 0; nt < 2; ++nt)
#pragma unroll
            for (int rg = 0; rg < 4; ++rg) {
                int px = (w * 4 + m) * 16 + lg * 4 + rg;
                int e = nt * 16 + lm;
                *(float*)(lds + swz(px * 128 + e * 4)) = acc[m][nt][rg];
            }
    __syncthreads();
    {
        int px = tid, r = px >> 4, cl = px & 15;
        float v[32];
#pragma unroll
        for (int h = 0; h < 8; ++h) {
            float4 q = *(const float4*)(lds + swz(px * 128 + h * 16));
            v[h * 4 + 0] = q.x; v[h * 4 + 1] = q.y; v[h * 4 + 2] = q.z; v[h * 4 + 3] = q.w;
        }
        float z[9];
#pragma unroll
        for (int i = 0; i < 9; ++i) z[i] = kb2[i];
#pragma unroll
        for (int e = 0; e < 32; ++e) {
            float ae = fmaxf(v[e], 0.f);
#pragma unroll
            for (int i = 0; i < 9; ++i)
                z[i] += ae * kw2[i * 32 + e];
        }
        float m = z[0];
#pragma unroll
        for (int i = 1; i < 9; ++i) m = fmaxf(m, z[i]);
        float sum = 0.f;
#pragma unroll
        for (int i = 0; i < 9; ++i) { z[i] = expf(z[i] - m); sum += z[i]; }
        float inv = 1.f / sum;
#pragma unroll
        for (int i = 0; i < 9; ++i) z[i] *= inv;
        int yq = ty0 + r, xq = tx0 + cl;
        size_t gp = ((size_t)(b * 16384 + (yq >> 1) * 128 + (xq >> 1))) * 48
                  + ((yq & 1) * 2 + (xq & 1)) * 12;
        float4* dp = (float4*)(kern48 + gp);
        float4 o0, o1, o2;
        o0.x = z[0]; o0.y = z[1]; o0.z = z[2]; o0.w = z[3];
        o1.x = z[4]; o1.y = z[5]; o1.z = z[6]; o1.w = z[7];
        o2.x = z[8]; o2.y = 0.f;  o2.z = 0.f;  o2.w = 0.f;
        dp[0] = o0; dp[1] = o1; dp[2] = o2;
    }
}

// ---- CARAFE reassembly: 8-ch chunks, replication-collapsed taps --------
__global__ __launch_bounds__(256) void k_out2(
    const float* __restrict__ feat, const float* __restrict__ kern48,
    float* __restrict__ out)
{
    __shared__ __align__(16) char smf[10368];   // 324 px * 8 ch fp32
    int tid = threadIdx.x;
    int blk = blockIdx.x;                 // 2048 = b(2) * chunk(16) * tile(64)
    int b = blk >> 10;
    int chunk = (blk >> 6) & 15;
    int tile = blk & 63;
    int ty0 = (tile >> 3) << 4, tx0 = (tile & 7) << 4;

    for (int i = tid; i < 648; i += 256) {
        int c4 = i / 324, px = i - c4 * 324;
        int r = px / 18, cl = px - r * 18;
        int yy = ty0 + r - 1, xx = tx0 + cl - 1;
        float4 v; v.x = 0.f; v.y = 0.f; v.z = 0.f; v.w = 0.f;
        if (yy >= 0 && yy < 128 && xx >= 0 && xx < 128) {
            int c0 = chunk * 8 + c4 * 4;
            size_t base = ((size_t)(b * 128 + c0) << 14) + yy * 128 + xx;
            v.x = feat[base];
            v.y = feat[base + (1 << 14)];
            v.z = feat[base + (2 << 14)];
            v.w = feat[base + (3 << 14)];
        }
        *(float4*)(smf + swz(px * 32 + c4 * 16)) = v;
    }
    __syncthreads();

    int r = tid >> 4, cl = tid & 15;
    int y = ty0 + r, x = tx0 + cl;

    // contiguous 192B kernel read per thread (lowres-major kern48 layout)
    const float* kp = kern48 + ((size_t)(b * 16384 + y * 128 + x)) * 48;
    float k4[2][2][9];
#pragma unroll
    for (int ry = 0; ry < 2; ++ry)
#pragma unroll
        for (int rx = 0; rx < 2; ++rx) {
            const float4* q = (const float4*)(kp + (ry * 2 + rx) * 12);
            float4 q0 = q[0], q1 = q[1], q2 = q[2];
            k4[ry][rx][0] = q0.x; k4[ry][rx][1] = q0.y; k4[ry][rx][2] = q0.z;
            k4[ry][rx][3] = q0.w; k4[ry][rx][4] = q1.x; k4[ry][rx][5] = q1.y;
            k4[ry][rx][6] = q1.z; k4[ry][rx][7] = q1.w; k4[ry][rx][8] = q2.x;
        }

    const int jmap[2][3] = { {0, 1, 1}, {1, 1, 2} };
    float acc[8][4];
#pragma unroll
    for (int ch = 0; ch < 8; ++ch)
#pragma unroll
        for (int o = 0; o < 4; ++o) acc[ch][o] = 0.f;

#pragma unroll
    for (int ny = 0; ny < 3; ++ny)
#pragma unroll
        for (int nx = 0; nx < 3; ++nx) {
            float co[2][2];
#pragma unroll
            for (int ry = 0; ry < 2; ++ry)
#pragma unroll
                for (int rx = 0; rx < 2; ++rx) {
                    float s = 0.f;
#pragma unroll
                    for (int a = 0; a < 3; ++a)
#pragma unroll
                        for (int bq = 0; bq < 3; ++bq)
                            if (jmap[ry][a] == ny && jmap[rx][bq] == nx)
                                s += k4[ry][rx][a * 3 + bq];
                    co[ry][rx] = s;
                }
            int px = (r + ny) * 18 + cl + nx;
            float4 f0 = *(const float4*)(smf + swz(px * 32));
            float4 f1 = *(const float4*)(smf + swz(px * 32 + 16));
            float fv[8] = { f0.x, f0.y, f0.z, f0.w, f1.x, f1.y, f1.z, f1.w };
#pragma unroll
            for (int ch = 0; ch < 8; ++ch) {
                acc[ch][0] += co[0][0] * fv[ch];
                acc[ch][1] += co[0][1] * fv[ch];
                acc[ch][2] += co[1][0] * fv[ch];
                acc[ch][3] += co[1][1] * fv[ch];
            }
        }

#pragma unroll
    for (int ch = 0; ch < 8; ++ch) {
        int c = chunk * 8 + ch;
        size_t base = (((size_t)(b * 128 + c) * 256 + 2 * y) * 256 + 2 * x);
        float2 o0, o1;
        o0.x = acc[ch][0]; o0.y = acc[ch][1];
        o1.x = acc[ch][2]; o1.y = acc[ch][3];
        *(float2*)(out + base) = o0;
        *(float2*)(out + base + 256) = o1;
    }
}

extern "C" void kernel_launch(void* const* d_in, const int* in_sizes, int n_in,
                              void* d_out, int out_size, void* d_ws, size_t ws_size,
                              hipStream_t stream)
{
    const float* feat  = (const float*)d_in[0];
    const float* guide = (const float*)d_in[1];
    const float* g_w1  = (const float*)d_in[2];
    const float* g_g1  = (const float*)d_in[3];
    const float* g_b1  = (const float*)d_in[4];
    const float* g_w2  = (const float*)d_in[5];
    const float* g_g2  = (const float*)d_in[6];
    const float* g_b2  = (const float*)d_in[7];
    const float* p_w   = (const float*)d_in[8];
    const float* k_w1  = (const float*)d_in[9];
    const float* k_w2  = (const float*)d_in[10];
    const float* k_b2  = (const float*)d_in[11];

    float* out = (float*)d_out;

    // bf16 NHWC intermediates inside d_out (dead before k_out2 writes):
    ushort_t* x1 = (ushort_t*)out;                    // 4,194,304 bf16 = 8.4MB
    ushort_t* x2 = (ushort_t*)(out + 2097152);        // 4,194,304 bf16

    // workspace layout
    float*    kern48 = (float*)d_ws;                  // 1,572,864 f32 (6.3MB)
    ushort_t* fs     = (ushort_t*)((char*)d_ws + 6291456);   // 1,048,576 bf16
    ushort_t* wpk    = (ushort_t*)((char*)d_ws + 8388608);   // 27,648 bf16
    float*    part   = (float*)((char*)d_ws + 8454144);      // 256*64 f32 = 64KB
    float*    ab1    = (float*)((char*)d_ws + 8519680);      // 64 f32
    float*    ab2    = (float*)((char*)d_ws + 8519936);      // 64 f32
    ushort_t* w2pk   = wpk;
    ushort_t* kw1pk  = wpk + 9216;

    k_phase1<<<1132, 256, 0, stream>>>(guide, g_w1, feat, p_w, g_w2, k_w1,
                                       x1, fs, wpk);
    k_statsP<<<256, 256, 0, stream>>>(x1, part);
    k_statsF<<<1, 64, 0, stream>>>(part, g_g1, g_b1, ab1);
    k_conv2_m<<<512, 256, 0, stream>>>(x1, ab1, w2pk, x2);
    k_statsP<<<256, 256, 0, stream>>>(x2, part);
    k_statsF<<<1, 64, 0, stream>>>(part, g_g2, g_b2, ab2);
    k_kern_m<<<512, 256, 0, stream>>>(x2, ab2, fs, kw1pk, k_w2, k_b2, kern48);
    k_out2<<<2048, 256, 0, stream>>>(feat, kern48, out);
}